// Round 4
// baseline (310.928 us; speedup 1.0000x reference)
//
#include <hip/hip_runtime.h>
#include <stdint.h>

#define NB 32
#define NN 524288
#define NPTS 16384
#define NBLK (NN / 1024)   // 512 K1 blocks per batch, 1024 points each
#define BCAP 96            // per-block candidate cap (mean 34.3, sd 5.8 -> 10.7 sigma)
#define SCAP 20480         // scatter buffer per batch (>= 16384 + max bin ~30)
#define NBINS 4096
#define THRESH 0.0478515625f   // 3136/65536 exact; u_(16384)~0.0448, 9-sigma

struct Keys { uint32_t k[2 * NB]; };

__host__ __device__ static inline void tf2x32(uint32_t k0, uint32_t k1,
                                              uint32_t x0, uint32_t x1,
                                              uint32_t* o0, uint32_t* o1) {
  uint32_t ks2 = k0 ^ k1 ^ 0x1BD11BDAu;
  x0 += k0; x1 += k1;
#define TFR(r) { x0 += x1; x1 = (x1 << (r)) | (x1 >> (32 - (r))); x1 ^= x0; }
  TFR(13) TFR(15) TFR(26) TFR(6)
  x0 += k1; x1 += ks2 + 1u;
  TFR(17) TFR(29) TFR(16) TFR(24)
  x0 += ks2; x1 += k0 + 2u;
  TFR(13) TFR(15) TFR(26) TFR(6)
  x0 += k0; x1 += k1 + 3u;
  TFR(17) TFR(29) TFR(16) TFR(24)
  x0 += k1; x1 += ks2 + 4u;
  TFR(13) TFR(15) TFR(26) TFR(6)
  x0 += ks2; x1 += k0 + 5u;
#undef TFR
  *o0 = x0; *o1 = x1;
}

// K1: threefry FIRST, load point ONLY if u < THRESH (4.8%). Per-block
// private candidate region + unconditional count write -> no memset, no
// global atomics anywhere in this kernel. float2+scalar sparse load.
__global__ __launch_bounds__(256) void k_candidates(
    const float* __restrict__ p, Keys keys,
    uint64_t* __restrict__ cand, uint32_t* __restrict__ blkcnt) {
  const int b = blockIdx.y;
  const int bx = blockIdx.x;
  const int t = threadIdx.x;
  const int i0 = (bx * 256 + t) * 4;            // first of 4 points
  const uint32_t kp0 = keys.k[2 * b], kp1 = keys.k[2 * b + 1];
  const float* pb = p + (size_t)b * NN * 3;
  typedef float f2 __attribute__((ext_vector_type(2), aligned(4)));

  uint64_t mykeys[4];
  int nc = 0;
#pragma unroll
  for (int j = 0; j < 4; ++j) {
    uint32_t o0, o1;
    tf2x32(kp0, kp1, 0u, (uint32_t)(i0 + j), &o0, &o1);
    uint32_t bits = o0 ^ o1;
    float u = __uint_as_float((bits >> 9) | 0x3F800000u) - 1.0f;
    if (u < THRESH) {
      const float* pp = pb + 3 * (size_t)(i0 + j);
      f2 v = *(const f2*)pp;                     // 4B-aligned vector load
      float z = pp[2];
      if (((v.x + v.y) + z) != 0.0f)             // reference's reduce order
        mykeys[nc++] = ((uint64_t)__float_as_uint(u) << 32) | (uint32_t)(i0 + j);
    }
  }

  __shared__ uint32_t lcnt;
  if (t == 0) lcnt = 0u;
  __syncthreads();
  uint32_t loc = 0u;
  if (nc) loc = atomicAdd(&lcnt, (uint32_t)nc);
  __syncthreads();
  uint64_t* cb = cand + ((size_t)b * NBLK + bx) * BCAP;
  for (int j = 0; j < nc; ++j) {
    uint32_t sl = loc + j;
    if (sl < BCAP) cb[sl] = mykeys[j];
  }
  if (t == 0) blkcnt[b * NBLK + bx] = (lcnt > BCAP) ? BCAP : lcnt;  // always written
}

// K23: one 1024-thread block per batch. Drains the 512 per-block regions
// (2 threads/region) into an LDS histogram, LDS-scans 4096 bins, then
// scatters via LDS fill counters into global bin-contiguous slots.
// Publishes cum + scount for K4.
__global__ __launch_bounds__(1024) void k_scan_scatter(
    const uint64_t* __restrict__ cand, const uint32_t* __restrict__ blkcnt,
    uint32_t* __restrict__ cum, uint32_t* __restrict__ scount,
    uint64_t* __restrict__ sorted) {
  const int b = blockIdx.x;
  const int t = threadIdx.x;
  const int lane = t & 63, wave = t >> 6;
  __shared__ uint32_t lhist[NBINS];          // phase 2: reused as fill
  __shared__ uint32_t lcum[NBINS + 1];
  __shared__ uint32_t wsum[16];
  __shared__ uint32_t lc[NBLK];

  for (int i = t; i < NBINS; i += 1024) lhist[i] = 0u;
  if (t < NBLK) {
    uint32_t M = blkcnt[b * NBLK + t];
    lc[t] = (M > BCAP) ? BCAP : M;
  }
  __syncthreads();

  // ---- LDS histogram: 2 threads drain each region ----
  {
    const int r = t >> 1;
    const uint32_t M = lc[r];
    const uint64_t* cb = cand + ((size_t)b * NBLK + r) * BCAP;
    for (uint32_t j = (uint32_t)(t & 1); j < M; j += 2) {
      uint32_t ub = (uint32_t)(cb[j] >> 32);
      atomicAdd(&lhist[(int)(__uint_as_float(ub) * 65536.0f)], 1u);
    }
  }
  __syncthreads();

  // ---- exclusive scan of 4096 bins (4 per thread, 2-level wave scan) ----
  uint32_t h0 = lhist[4 * t], h1 = lhist[4 * t + 1],
           h2 = lhist[4 * t + 2], h3 = lhist[4 * t + 3];
  uint32_t s4 = h0 + h1 + h2 + h3;
  uint32_t v = s4;
  for (int off = 1; off < 64; off <<= 1) {
    uint32_t n = __shfl_up(v, off, 64);
    if (lane >= off) v += n;
  }
  if (lane == 63) wsum[wave] = v;
  __syncthreads();
  if (t < 16) {
    uint32_t w = wsum[t];
    for (int off = 1; off < 16; off <<= 1) {
      uint32_t n = __shfl_up(w, off, 64);
      if (t >= off) w += n;
    }
    wsum[t] = w;
  }
  __syncthreads();
  uint32_t incl = v + (wave ? wsum[wave - 1] : 0u);
  uint32_t c[5];
  c[0] = incl - s4; c[1] = c[0] + h0; c[2] = c[1] + h1;
  c[3] = c[2] + h2; c[4] = incl;
  lcum[4 * t] = c[0]; lcum[4 * t + 1] = c[1];
  lcum[4 * t + 2] = c[2]; lcum[4 * t + 3] = c[3];
  if (t == 1023) lcum[NBINS] = incl;
  uint32_t* gc = cum + (size_t)b * (NBINS + 1);
  gc[4 * t] = c[0]; gc[4 * t + 1] = c[1];
  gc[4 * t + 2] = c[2]; gc[4 * t + 3] = c[3];
  if (t == 1023) gc[NBINS] = incl;
#pragma unroll
  for (int q = 0; q < 4; ++q)
    if (c[q] < NPTS && c[q + 1] >= NPTS) {
      uint32_t sc = c[q + 1];
      scount[b] = (sc > SCAP) ? SCAP : sc;
    }
  if (t == 1023 && incl < NPTS) scount[b] = incl;   // defensive

  // ---- reuse lhist as fill, scatter via LDS cum ----
  for (int i = t; i < NBINS; i += 1024) lhist[i] = 0u;
  __syncthreads();
  {
    const int r = t >> 1;
    const uint32_t M = lc[r];
    const uint64_t* cb = cand + ((size_t)b * NBLK + r) * BCAP;
    for (uint32_t j = (uint32_t)(t & 1); j < M; j += 2) {
      uint64_t key = cb[j];
      int bin = (int)(__uint_as_float((uint32_t)(key >> 32)) * 65536.0f);
      uint32_t c0 = lcum[bin];
      if (c0 < NPTS) {                       // bin fully past rank 16384?
        uint32_t pos = atomicAdd(&lhist[bin], 1u);
        uint32_t sl = c0 + pos;
        if (sl < SCAP) sorted[(size_t)b * SCAP + sl] = key;
      }
    }
  }
}

// K4: thread-per-slot exact rank (count smaller keys in own bin), gather
// p[idx], emit. Keys unique -> exact stable order, bit-identical to argsort.
__global__ __launch_bounds__(256) void k_rank(
    const float* __restrict__ p, const uint64_t* __restrict__ sorted,
    const uint32_t* __restrict__ cum, const uint32_t* __restrict__ scount,
    float* __restrict__ out) {
  const int b = blockIdx.y;
  const uint32_t j = blockIdx.x * 256 + threadIdx.x;
  if (j >= scount[b]) return;
  const uint64_t* sb = sorted + (size_t)b * SCAP;
  uint64_t key = sb[j];
  float u = __uint_as_float((uint32_t)(key >> 32));
  int bin = (int)(u * 65536.0f);
  const uint32_t* gc = cum + (size_t)b * (NBINS + 1);
  uint32_t c0 = gc[bin], c1 = gc[bin + 1];
  uint32_t r = c0;
  for (uint32_t l = c0; l < c1; ++l) r += (sb[l] < key) ? 1u : 0u;
  if (r < NPTS) {
    uint32_t idx = (uint32_t)key;
    const float* pp = p + (size_t)b * NN * 3 + 3 * (size_t)idx;
    float* o = out + ((size_t)b * NPTS + r) * 3;
    o[0] = pp[0]; o[1] = pp[1]; o[2] = pp[2];
  }
}

extern "C" void kernel_launch(void* const* d_in, const int* in_sizes, int n_in,
                              void* d_out, int out_size, void* d_ws, size_t ws_size,
                              hipStream_t stream) {
  const float* p = (const float*)d_in[0];
  float* out = (float*)d_out;
  uint8_t* ws = (uint8_t*)d_ws;

  size_t off_cand   = 0;                                            // 12.58 MB
  size_t off_sorted = off_cand + (size_t)NB * NBLK * BCAP * 8;      // +5.24 MB
  size_t off_cum    = off_sorted + (size_t)NB * SCAP * 8;           // +0.52 MB
  size_t off_scnt   = off_cum + (size_t)NB * (NBINS + 1) * 4;       // +128 B
  size_t off_bcnt   = off_scnt + 128;                               // +64 KB

  uint64_t* cand   = (uint64_t*)(ws + off_cand);
  uint64_t* sorted = (uint64_t*)(ws + off_sorted);
  uint32_t* cum    = (uint32_t*)(ws + off_cum);
  uint32_t* scount = (uint32_t*)(ws + off_scnt);
  uint32_t* blkcnt = (uint32_t*)(ws + off_bcnt);

  // Host-side threefry key derivation (partitionable mode, verified absmax=0):
  // key(42) -> split(32) via cipher(key,(0,b)) -> split(2)[0] via cipher(kb,(0,0)).
  Keys keys;
  for (int b = 0; b < NB; ++b) {
    uint32_t kb0, kb1, kp0, kp1;
    tf2x32(0u, 42u, 0u, (uint32_t)b, &kb0, &kb1);
    tf2x32(kb0, kb1, 0u, 0u, &kp0, &kp1);
    keys.k[2 * b] = kp0; keys.k[2 * b + 1] = kp1;
  }

  // No memset: every blkcnt word is rewritten by K1 each launch (poison-proof).
  dim3 g1(NBLK, NB);               // 4 points per thread
  k_candidates<<<g1, 256, 0, stream>>>(p, keys, cand, blkcnt);
  k_scan_scatter<<<NB, 1024, 0, stream>>>(cand, blkcnt, cum, scount, sorted);
  dim3 g4(SCAP / 256, NB);
  k_rank<<<g4, 256, 0, stream>>>(p, sorted, cum, scount, out);
}